// Round 8
// baseline (76.479 us; speedup 1.0000x reference)
//
#include <hip/hip_runtime.h>
#include <hip/hip_bf16.h>

// Problem: B=512, S=256, E=384, H=64.
// d_in: x [B,S,E] f32; Wq,Wk,Wv [E,H] f32.  d_out: [B,S,H] f32.
// ws: [0, 147456) wfrag bf16 (only region used).
//
// FUSED v8 = v6's 12-wave geometry + v7's three verified fixes:
//  (1) af W-fragments pinned via empty-asm "+v"  -- v6's 12-wave attempt
//      failed ONLY because the allocator dropped af residency (VGPR=84<96);
//      v7 proved the pin prevents that.
//  (2) single barrier per chunk (9 total), dbuf-justified (v7-verified).
//  (3) v7's lean attention: in-lane P, zero barriers, s_setprio around MFMA.
// Geometry: 768 threads = 12 waves, 2 row-groups x 6 col-waves (2 h-tiles
// each -> af[12][2] = 96 VGPR pinned). LDS 96 KB QKV + 48 KB staging =
// 147456 B -> 1 block/CU, 3 waves/SIMD (12 waves/CU vs v7's 8).

#define NB   512
#define SS   256
#define EE   384
#define HH   64

typedef short bf16x8 __attribute__((ext_vector_type(8)));
typedef float f32x4  __attribute__((ext_vector_type(4)));

__device__ __forceinline__ short f2bf(float f) {
  union { float f; unsigned u; } x; x.f = f;
  unsigned r = x.u + 0x7fffu + ((x.u >> 16) & 1u);
  return (short)(r >> 16);
}

// ---------------- prep: W -> fragment-ordered bf16 (unchanged) ----------------
// wfrag[((ks*12+nf)*64 + lane)*8 + j] = Wcat[ks*32 + (lane>>4)*8 + j][nf*16 + (lane&15)]
__global__ __launch_bounds__(256) void prep_w_kernel(
    const float* __restrict__ Wq, const float* __restrict__ Wk,
    const float* __restrict__ Wv, short* __restrict__ wfrag) {
  int t = blockIdx.x * 256 + threadIdx.x;
  if (t >= 12 * 12 * 64) return;
  int ks  = t / (12 * 64);
  int rem = t % (12 * 64);
  int nf  = rem / 64;
  int l   = rem % 64;
  int l15 = l & 15, lhi = l >> 4;
  int ncat = nf * 16 + l15;
  const float* W = (ncat < 64) ? Wq : (ncat < 128 ? Wk : Wv);
  int n = ncat & 63;
  short* dst = wfrag + (size_t)t * 8;
#pragma unroll
  for (int j = 0; j < 8; ++j) {
    int kk = ks * 32 + lhi * 8 + j;
    dst[j] = f2bf(W[kk * 64 + n]);
  }
}

// ---------------- fused: one block = one batch, 12 waves, 144 KB LDS ----------------
__global__ __launch_bounds__(768, 3) void fused_kernel(
    const float* __restrict__ x, const short* __restrict__ wfrag,
    float* __restrict__ out) {
  // Ql swizzled: elem (row,h) at Ql[row*64 + (h ^ ((row&7)<<3))]       (v2/v5/v7-verified)
  // Kl swizzled: elem (row,h) at Kl[row*64 + (h ^ (srow<<3))],
  //              srow = ((row&8)>>1)|(row&3)                           (v4..v7-verified)
  // Vt swizzled: elem (h,row) at Vt[h*256 + (row ^ ((h&7)<<3))]        (v2..v7-verified)
  // xst: per group g, dbuf of 16-row x tiles; 8-float group cg of row r
  //      stored at ((cg ^ (r&7))*8)                                    (v6-verified)
  __shared__ __align__(16) short Ql[SS * HH];      // 32 KB
  __shared__ __align__(16) short Kl[SS * HH];      // 32 KB
  __shared__ __align__(16) short Vt[HH * SS];      // 32 KB
  __shared__ __align__(16) short xst[4 * 16 * EE]; // 48 KB -> 147456 B total

  int b    = blockIdx.x;
  int tid  = threadIdx.x;
  int lane = tid & 63, wv = tid >> 6;              // wv in [0,12)
  int l15  = lane & 15, lhi = lane >> 4;
  int sw   = l15 & 7;
  int g    = wv / 6;                               // row group: rows [g*128, g*128+128)
  int wg   = wv % 6;                               // col-split role: h-tiles f = wg*2+ht
  int tg   = tid - g * 384;                        // thread index within group [0,384)
  const float* xb = x + (size_t)b * SS * EE;

  // ---- W fragments resident: 2 h-tiles/wave -> af[12][2] = 96 VGPR, pinned ----
  bf16x8 af[12][2];
#pragma unroll
  for (int ks = 0; ks < 12; ++ks)
#pragma unroll
    for (int ht = 0; ht < 2; ++ht)
      af[ks][ht] = *(const bf16x8*)(wfrag + ((size_t)(ks * 12 + wg * 2 + ht) * 64 + lane) * 8);
  // Pin: values opaque -> allocator cannot rematerialize wfrag loads in the
  // K-loop (v5/v6 failure: VGPR_Count 108/84 < af size, per-MFMA reloads).
#pragma unroll
  for (int ks = 0; ks < 12; ++ks)
#pragma unroll
    for (int ht = 0; ht < 2; ++ht)
      asm volatile("" : "+v"(af[ks][ht]));

  f32x4 st[4];
  auto loadch = [&](int ch) {  // group stages 16 rows = 24 KB f32, 64 B/thread
    const float* p0 = xb + (size_t)(g * 128 + ch * 16) * EE;
#pragma unroll
    for (int i = 0; i < 4; ++i)
      st[i] = *(const f32x4*)(p0 + (size_t)(tg + 384 * i) * 4);
  };
  auto writech = [&](short* xl) {  // regs -> bf16 -> swizzled LDS (8 B stores)
#pragma unroll
    for (int i = 0; i < 4; ++i) {
      int c16 = tg + 384 * i;        // 16B-f32 chunk: row = c16/96, cg4 = c16%96
      int row = c16 / 96, cg4 = c16 % 96;
      union { short4 s4; __hip_bfloat162 h2[2]; } u;
      u.h2[0] = __float22bfloat162_rn(make_float2(st[i][0], st[i][1]));
      u.h2[1] = __float22bfloat162_rn(make_float2(st[i][2], st[i][3]));
      *(short4*)(xl + row * 384 + (((cg4 >> 1) ^ (row & 7)) * 8 + (cg4 & 1) * 4)) = u.s4;
    }
  };

  // ---- projection: per group 8 chunks of 16 rows, dbuf, ONE barrier/chunk ----
  // Single-barrier safety (v7-verified): writech(ch+1) targets the opposite
  // buffer of the one being read; reads of that buffer happened in iteration
  // ch-1 and are retired by the barrier at iteration ch's top.
  loadch(0);
  writech(xst + (g * 2) * (16 * EE));
  for (int ch = 0; ch < 8; ++ch) {
    if (ch < 7) loadch(ch + 1);      // issue next chunk's loads before the barrier
    __syncthreads();                 // buf(ch&1) written; old reads of other buf done
    const short* xl = xst + (g * 2 + (ch & 1)) * (16 * EE);

    f32x4 acc[2];
    acc[0] = (f32x4){0.f, 0.f, 0.f, 0.f};
    acc[1] = (f32x4){0.f, 0.f, 0.f, 0.f};
#pragma unroll
    for (int ks = 0; ks < 12; ++ks) {
      bf16x8 bx = *(const bf16x8*)(xl + l15 * 384 + (((ks * 4 + lhi) ^ sw) * 8));
      acc[0] = __builtin_amdgcn_mfma_f32_16x16x32_bf16(af[ks][0], bx, acc[0], 0, 0, 0);
      acc[1] = __builtin_amdgcn_mfma_f32_16x16x32_bf16(af[ks][1], bx, acc[1], 0, 0, 0);
    }

    // epilogue: f = wg*2+ht (wave-uniform), ncat = f*16+lhi*4, row = g*128+ch*16+l15
    int row  = g * 128 + ch * 16 + l15;
    int srow = ((row & 8) >> 1) | (row & 3);
#pragma unroll
    for (int ht = 0; ht < 2; ++ht) {
      int f = wg * 2 + ht;
      int ncat = f * 16 + lhi * 4;
      if (f < 4) {          // Q -> Ql, row&7 swizzle
        union { short4 s4; __hip_bfloat162 h2[2]; } oq;
        oq.h2[0] = __float22bfloat162_rn(make_float2(acc[ht][0], acc[ht][1]));
        oq.h2[1] = __float22bfloat162_rn(make_float2(acc[ht][2], acc[ht][3]));
        *(short4*)(Ql + row * 64 + (ncat ^ ((row & 7) << 3))) = oq.s4;
      } else if (f < 8) {   // K -> Kl, srow swizzle
        int col = ncat - 64;
        union { short4 s4; __hip_bfloat162 h2[2]; } ok;
        ok.h2[0] = __float22bfloat162_rn(make_float2(acc[ht][0], acc[ht][1]));
        ok.h2[1] = __float22bfloat162_rn(make_float2(acc[ht][2], acc[ht][3]));
        *(short4*)(Kl + row * 64 + (col ^ (srow << 3))) = ok.s4;
      } else {              // V -> Vt transposed, scalar stores
#pragma unroll
        for (int j = 0; j < 4; ++j) {
          int h = ncat - 128 + j;
          Vt[h * 256 + (row ^ ((h & 7) << 3))] = f2bf(acc[ht][j]);
        }
      }
    }
    if (ch < 7) writech(xst + (g * 2 + ((ch + 1) & 1)) * (16 * EE));
  }
  __syncthreads();                   // Ql/Kl/Vt complete (9th and last barrier)

  // ---- attention: 12-wave balanced causal partition, in-lane P, zero barriers ----
  // w0:{15} w1:{14} w2:{13} w3:{12} w4:{11,0} w5:{10,1} w6:{9,2} w7:{8,3}
  // w8:{7,4} w9:{6,5} w10,w11: idle
  int nt, rt0 = 0, rt1 = 0;
  if (wv < 4)       { nt = 1; rt0 = 15 - wv; }
  else if (wv < 10) { nt = 2; rt0 = 15 - wv; rt1 = wv - 4; }
  else              { nt = 0; }

  size_t obase = (size_t)b * SS * HH;
  for (int u = 0; u < nt; ++u) {
    int rt    = (u == 0) ? rt0 : rt1;
    int qrow0 = rt * 16;
    int twp   = (rt + 2) & ~1;       // even # of interleaved 16-row k-tiles
    int nk    = twp >> 1;            // 32-k PV chunks
    int qg    = qrow0 + l15;         // this lane's q-row (P lives at q=l15)

    // Q fragments from swizzled Ql
    int qlrow = qrow0 + l15;
    bf16x8 qa0 = *(const bf16x8*)(Ql + qlrow * 64 + ((lhi * 8) ^ ((qlrow & 7) << 3)));
    bf16x8 qa1 = *(const bf16x8*)(Ql + qlrow * 64 + ((32 + lhi * 8) ^ ((qlrow & 7) << 3)));

    // scores: tile t loads K rows kc = (t>>1)*32 + (l15>>2)*8 + (t&1)*4 + (l15&3)
    // (interleaved mapping: srow(kc) == sw, and D-layout == PV A-fragment)
    f32x4 s[16];
#pragma unroll
    for (int t = 0; t < 16; ++t) {
      if (t >= twp) continue;
      int kc = (t >> 1) * 32 + ((l15 >> 2) << 3) + ((t & 1) << 2) + (l15 & 3);
      const short* kp = Kl + kc * 64;
      bf16x8 kb0 = *(const bf16x8*)(kp + ((lhi * 8) ^ (sw << 3)));
      bf16x8 kb1 = *(const bf16x8*)(kp + ((32 + lhi * 8) ^ (sw << 3)));
      __builtin_amdgcn_s_setprio(1);
      f32x4 a = (f32x4){0.f, 0.f, 0.f, 0.f};
      a = __builtin_amdgcn_mfma_f32_16x16x32_bf16(kb0, qa0, a, 0, 0, 0);
      a = __builtin_amdgcn_mfma_f32_16x16x32_bf16(kb1, qa1, a, 0, 0, 0);
      __builtin_amdgcn_s_setprio(0);
#pragma unroll
      for (int r = 0; r < 4; ++r) {
        int kg = (t >> 1) * 32 + lhi * 8 + ((t & 1) << 2) + r;
        s[t][r] = (kg <= qg) ? a[r] * 0.125f : -INFINITY;
      }
    }

    // softmax over lane-local row (q=l15), reduce across lhi groups
    float mx = -3.0e38f;
#pragma unroll
    for (int t = 0; t < 16; ++t) {
      if (t >= twp) continue;
#pragma unroll
      for (int r = 0; r < 4; ++r) mx = fmaxf(mx, s[t][r]);
    }
    mx = fmaxf(mx, __shfl_xor(mx, 16));
    mx = fmaxf(mx, __shfl_xor(mx, 32));
    float sm = 0.f;
#pragma unroll
    for (int t = 0; t < 16; ++t) {
      if (t >= twp) continue;
#pragma unroll
      for (int r = 0; r < 4; ++r) {
        float p = __expf(s[t][r] - mx);    // exp(-inf)=0
        s[t][r] = p;
        sm += p;
      }
    }
    sm += __shfl_xor(sm, 16);
    sm += __shfl_xor(sm, 32);
    float inv = 1.f / sm;
    float invq[4];
#pragma unroll
    for (int r = 0; r < 4; ++r) invq[r] = __shfl(inv, lhi * 4 + r);

    // PV: pack P in-lane (no LDS), accumulate
    f32x4 o[4];
#pragma unroll
    for (int nf = 0; nf < 4; ++nf) o[nf] = (f32x4){0.f, 0.f, 0.f, 0.f};
#pragma unroll
    for (int kc2 = 0; kc2 < 8; ++kc2) {
      if (kc2 >= nk) continue;
      union { bf16x8 v; __hip_bfloat162 h2[4]; } pu;
      pu.h2[0] = __float22bfloat162_rn(make_float2(s[2*kc2][0],   s[2*kc2][1]));
      pu.h2[1] = __float22bfloat162_rn(make_float2(s[2*kc2][2],   s[2*kc2][3]));
      pu.h2[2] = __float22bfloat162_rn(make_float2(s[2*kc2+1][0], s[2*kc2+1][1]));
      pu.h2[3] = __float22bfloat162_rn(make_float2(s[2*kc2+1][2], s[2*kc2+1][3]));
      int kofs = kc2 * 32 + lhi * 8;
      __builtin_amdgcn_s_setprio(1);
#pragma unroll
      for (int nf = 0; nf < 4; ++nf) {
        int hrow = nf * 16 + l15;
        bf16x8 vb = *(const bf16x8*)(Vt + hrow * 256 + (kofs ^ ((hrow & 7) << 3)));
        o[nf] = __builtin_amdgcn_mfma_f32_16x16x32_bf16(pu.v, vb, o[nf], 0, 0, 0);
      }
      __builtin_amdgcn_s_setprio(0);
    }

    // store (divide by row sum here)
#pragma unroll
    for (int nf = 0; nf < 4; ++nf)
#pragma unroll
      for (int r = 0; r < 4; ++r) {
        int q = qrow0 + lhi * 4 + r;
        int h = nf * 16 + l15;
        out[obase + (size_t)q * HH + h] = o[nf][r] * invq[r];
      }
  }
}

extern "C" void kernel_launch(void* const* d_in, const int* in_sizes, int n_in,
                              void* d_out, int out_size, void* d_ws, size_t ws_size,
                              hipStream_t stream) {
  const float* x  = (const float*)d_in[0];
  const float* Wq = (const float*)d_in[1];
  const float* Wk = (const float*)d_in[2];
  const float* Wv = (const float*)d_in[3];
  float* out = (float*)d_out;

  short* wfrag = (short*)d_ws;

  prep_w_kernel<<<36, 256, 0, stream>>>(Wq, Wk, Wv, wfrag);
  fused_kernel<<<512, 768, 0, stream>>>(x, wfrag, out);
}

// Round 9
// 60.203 us; speedup vs baseline: 1.2703x; 1.2703x over previous
//
#include <hip/hip_runtime.h>
#include <hip/hip_bf16.h>

// Problem: B=512, S=256, E=384, H=64.
// d_in: x [B,S,E] f32; Wq,Wk,Wv [E,H] f32.  d_out: [B,S,H] f32.
// ws: [0, 147456) wfrag bf16 (only region used).
//
// FUSED v9 = v7 (57.4us champion) + surgical duty-cycle package:
//  (1) 2-deep register prefetch (stA/stB, manual 2-unroll of the chunk loop
//      so st indices stay static -- no scratch): chunk ch+2's loads issue at
//      iter ch's top; writech consumes loads issued a FULL iteration earlier
//      -> ~900cy HBM latency fully covered, 2 chunks continuously in flight.
//  (2) loadch(0) issued BEFORE the af loads (x stream starts at cycle 0).
//  (3) exp2 fold in softmax (scale 0.125*log2e, exp2f) -- one v_mul fewer
//      per score element.
// Everything else byte-identical to v7 (af pin, 9 barriers, in-lane-P attn).

#define NB   512
#define SS   256
#define EE   384
#define HH   64

#define PR16  16            // x rows staged per chunk per group
#define LROW  392           // staging row stride in shorts (384 data + 8 pad)
#define XLSZ  (PR16 * LROW) // 6272 shorts per staging buffer

#define SCL2  0.18033688f   // 0.125 * log2(e)

typedef short bf16x8 __attribute__((ext_vector_type(8)));
typedef float f32x4  __attribute__((ext_vector_type(4)));

__device__ __forceinline__ short f2bf(float f) {
  union { float f; unsigned u; } x; x.f = f;
  unsigned r = x.u + 0x7fffu + ((x.u >> 16) & 1u);
  return (short)(r >> 16);
}

// ---------------- prep: W -> fragment-ordered bf16 (unchanged) ----------------
// wfrag[((ks*12+nf)*64 + lane)*8 + j] = Wcat[ks*32 + (lane>>4)*8 + j][nf*16 + (lane&15)]
__global__ __launch_bounds__(256) void prep_w_kernel(
    const float* __restrict__ Wq, const float* __restrict__ Wk,
    const float* __restrict__ Wv, short* __restrict__ wfrag) {
  int t = blockIdx.x * 256 + threadIdx.x;
  if (t >= 12 * 12 * 64) return;
  int ks  = t / (12 * 64);
  int rem = t % (12 * 64);
  int nf  = rem / 64;
  int l   = rem % 64;
  int l15 = l & 15, lhi = l >> 4;
  int ncat = nf * 16 + l15;
  const float* W = (ncat < 64) ? Wq : (ncat < 128 ? Wk : Wv);
  int n = ncat & 63;
  short* dst = wfrag + (size_t)t * 8;
#pragma unroll
  for (int j = 0; j < 8; ++j) {
    int kk = ks * 32 + lhi * 8 + j;
    dst[j] = f2bf(W[kk * 64 + n]);
  }
}

// ---------------- fused: one block = one batch, 8 waves, 148 KB LDS ----------------
__global__ __launch_bounds__(512, 2) void fused_kernel(
    const float* __restrict__ x, const short* __restrict__ wfrag,
    float* __restrict__ out) {
  // Ql swizzled: elem (row,h) at Ql[row*64 + (h ^ ((row&7)<<3))]       (v2/v5/v7-verified)
  // Kl swizzled: elem (row,h) at Kl[row*64 + (h ^ (srow<<3))],
  //              srow = ((row&8)>>1)|(row&3)                           (v4..v7-verified)
  // Vt swizzled: elem (h,row) at Vt[h*256 + (row ^ ((h&7)<<3))]        (v2..v7-verified)
  // xst: per group g, dbuf of 16-row tiles, padded stride LROW=392     (v2/v7-verified)
  __shared__ __align__(16) short Ql[SS * HH];    // 32 KB
  __shared__ __align__(16) short Kl[SS * HH];    // 32 KB
  __shared__ __align__(16) short Vt[HH * SS];    // 32 KB
  __shared__ __align__(16) short xst[4 * XLSZ];  // 49 KB -> 148480 B total

  int b    = blockIdx.x;
  int tid  = threadIdx.x;
  int lane = tid & 63, wv = tid >> 6;            // wv in [0,8)
  int l15  = lane & 15, lhi = lane >> 4;
  int sw   = l15 & 7;
  int g    = wv >> 2;                            // row group: rows [g*128, g*128+128)
  int wg   = wv & 3;                             // col-split role: h-tiles f = wg*3+ht
  int tg   = tid & 255;                          // thread index within group
  const float* xg = x + (size_t)b * SS * EE + (size_t)g * 128 * EE;

  f32x4 stA[6], stB[6];
  auto loadch = [&](int ch, f32x4 (&st)[6]) {  // 16 rows = 24 KB f32/group, contiguous
    const float* p0 = xg + (size_t)ch * PR16 * EE;
#pragma unroll
    for (int i = 0; i < 3; ++i) {
      const f32x4* p = (const f32x4*)(p0 + (size_t)(tg + 256 * i) * 8);
      st[2 * i]     = p[0];
      st[2 * i + 1] = p[1];
    }
  };
  auto writech = [&](const f32x4 (&st)[6], short* xl) {  // regs -> bf16 -> padded LDS
#pragma unroll
    for (int i = 0; i < 3; ++i) {
      int c = tg + 256 * i;          // 8-float group: row = c/48, cg = c%48
      int row = c / 48, cg = c % 48;
      union { bf16x8 vv; __hip_bfloat162 h2[4]; } u;
      u.h2[0] = __float22bfloat162_rn(make_float2(st[2*i][0],   st[2*i][1]));
      u.h2[1] = __float22bfloat162_rn(make_float2(st[2*i][2],   st[2*i][3]));
      u.h2[2] = __float22bfloat162_rn(make_float2(st[2*i+1][0], st[2*i+1][1]));
      u.h2[3] = __float22bfloat162_rn(make_float2(st[2*i+1][2], st[2*i+1][3]));
      *(bf16x8*)(xl + row * LROW + cg * 8) = u.vv;
    }
  };

  // ---- x stream starts FIRST; af loads (L2-hot) overlap it ----
  loadch(0, stA);

  // ---- W fragments resident: 3 h-tiles/wave, 36 x bf16x8 = 144 VGPR, pinned ----
  bf16x8 af[12][3];
#pragma unroll
  for (int ks = 0; ks < 12; ++ks)
#pragma unroll
    for (int ht = 0; ht < 3; ++ht)
      af[ks][ht] = *(const bf16x8*)(wfrag + ((size_t)(ks * 12 + wg * 3 + ht) * 64 + lane) * 8);
#pragma unroll
  for (int ks = 0; ks < 12; ++ks)
#pragma unroll
    for (int ht = 0; ht < 3; ++ht)
      asm volatile("" : "+v"(af[ks][ht]));

  // MFMA + epilogue for one chunk (identical to v7)
  auto compute = [&](int ch, const short* xl) {
    f32x4 acc[3];
#pragma unroll
    for (int ht = 0; ht < 3; ++ht) acc[ht] = (f32x4){0.f, 0.f, 0.f, 0.f};
#pragma unroll
    for (int ks = 0; ks < 12; ++ks) {
      bf16x8 bx = *(const bf16x8*)(xl + l15 * LROW + ks * 32 + lhi * 8);
#pragma unroll
      for (int ht = 0; ht < 3; ++ht)
        acc[ht] = __builtin_amdgcn_mfma_f32_16x16x32_bf16(af[ks][ht], bx, acc[ht], 0, 0, 0);
    }
    int row  = g * 128 + ch * PR16 + l15;
    int srow = ((row & 8) >> 1) | (row & 3);
#pragma unroll
    for (int ht = 0; ht < 3; ++ht) {
      int f = wg * 3 + ht;
      int ncat = f * 16 + lhi * 4;
      if (f < 4) {          // Q -> Ql, row&7 swizzle
        union { short4 s4; __hip_bfloat162 h2[2]; } oq;
        oq.h2[0] = __float22bfloat162_rn(make_float2(acc[ht][0], acc[ht][1]));
        oq.h2[1] = __float22bfloat162_rn(make_float2(acc[ht][2], acc[ht][3]));
        *(short4*)(Ql + row * 64 + (ncat ^ ((row & 7) << 3))) = oq.s4;
      } else if (f < 8) {   // K -> Kl, srow swizzle
        int col = ncat - 64;
        union { short4 s4; __hip_bfloat162 h2[2]; } ok;
        ok.h2[0] = __float22bfloat162_rn(make_float2(acc[ht][0], acc[ht][1]));
        ok.h2[1] = __float22bfloat162_rn(make_float2(acc[ht][2], acc[ht][3]));
        *(short4*)(Kl + row * 64 + (col ^ (srow << 3))) = ok.s4;
      } else {              // V -> Vt transposed, scalar stores
#pragma unroll
        for (int j = 0; j < 4; ++j) {
          int h = ncat - 128 + j;
          Vt[h * 256 + (row ^ ((h & 7) << 3))] = f2bf(acc[ht][j]);
        }
      }
    }
  };

  // ---- projection: 8 chunks, dbuf LDS + 2-deep reg prefetch, 1 barrier/chunk ----
  // Pre-loop: stA holds ch0 -> LDS buf0; stB holds ch1.
  writech(stA, xst + (g * 2) * XLSZ);
  loadch(1, stB);
  for (int k = 0; k < 4; ++k) {
    {                                  // ch = 2k (even): reads buf0, fills stA
      int ch = 2 * k;
      if (ch < 6) loadch(ch + 2, stA); // issue 2-ahead before the barrier
      __syncthreads();                 // buf0 written; old reads of buf1 retired
      compute(ch, xst + (g * 2) * XLSZ);
      if (ch < 7) writech(stB, xst + (g * 2 + 1) * XLSZ);  // chunk ch+1 -> buf1
    }
    {                                  // ch = 2k+1 (odd): reads buf1, fills stB
      int ch = 2 * k + 1;
      if (ch < 6) loadch(ch + 2, stB);
      __syncthreads();                 // buf1 written; old reads of buf0 retired
      compute(ch, xst + (g * 2 + 1) * XLSZ);
      if (ch < 7) writech(stA, xst + (g * 2) * XLSZ);      // chunk ch+1 -> buf0
    }
  }
  __syncthreads();                     // Ql/Kl/Vt complete (9th and last barrier)

  // ---- attention: tiles {wv, 15-wv}, in-lane P, zero barriers (v7-verified) ----
  size_t obase = (size_t)b * SS * HH;
#pragma unroll
  for (int u = 0; u < 2; ++u) {
    int rt    = (u == 0) ? wv : (15 - wv);
    int qrow0 = rt * 16;
    int twp   = (rt + 2) & ~1;       // even # of interleaved 16-row k-tiles
    int nk    = twp >> 1;            // 32-k PV chunks
    int qg    = qrow0 + l15;         // this lane's q-row (P lives at q=l15)

    // Q fragments from swizzled Ql
    int qlrow = qrow0 + l15;
    bf16x8 qa0 = *(const bf16x8*)(Ql + qlrow * 64 + ((lhi * 8) ^ ((qlrow & 7) << 3)));
    bf16x8 qa1 = *(const bf16x8*)(Ql + qlrow * 64 + ((32 + lhi * 8) ^ ((qlrow & 7) << 3)));

    // scores: tile t loads K rows kc = (t>>1)*32 + (l15>>2)*8 + (t&1)*4 + (l15&3)
    // (interleaved mapping: srow(kc) == sw, and D-layout == PV A-fragment)
    f32x4 s[16];
#pragma unroll
    for (int t = 0; t < 16; ++t) {
      if (t >= twp) continue;
      int kc = (t >> 1) * 32 + ((l15 >> 2) << 3) + ((t & 1) << 2) + (l15 & 3);
      const short* kp = Kl + kc * 64;
      bf16x8 kb0 = *(const bf16x8*)(kp + ((lhi * 8) ^ (sw << 3)));
      bf16x8 kb1 = *(const bf16x8*)(kp + ((32 + lhi * 8) ^ (sw << 3)));
      __builtin_amdgcn_s_setprio(1);
      f32x4 a = (f32x4){0.f, 0.f, 0.f, 0.f};
      a = __builtin_amdgcn_mfma_f32_16x16x32_bf16(kb0, qa0, a, 0, 0, 0);
      a = __builtin_amdgcn_mfma_f32_16x16x32_bf16(kb1, qa1, a, 0, 0, 0);
      __builtin_amdgcn_s_setprio(0);
#pragma unroll
      for (int r = 0; r < 4; ++r) {
        int kg = (t >> 1) * 32 + lhi * 8 + ((t & 1) << 2) + r;
        s[t][r] = (kg <= qg) ? a[r] * SCL2 : -INFINITY;   // log2-domain scores
      }
    }

    // softmax (log2 domain) over lane-local row, reduce across lhi groups
    float mx = -3.0e38f;
#pragma unroll
    for (int t = 0; t < 16; ++t) {
      if (t >= twp) continue;
#pragma unroll
      for (int r = 0; r < 4; ++r) mx = fmaxf(mx, s[t][r]);
    }
    mx = fmaxf(mx, __shfl_xor(mx, 16));
    mx = fmaxf(mx, __shfl_xor(mx, 32));
    float sm = 0.f;
#pragma unroll
    for (int t = 0; t < 16; ++t) {
      if (t >= twp) continue;
#pragma unroll
      for (int r = 0; r < 4; ++r) {
        float p = exp2f(s[t][r] - mx);     // exp2(-inf)=0
        s[t][r] = p;
        sm += p;
      }
    }
    sm += __shfl_xor(sm, 16);
    sm += __shfl_xor(sm, 32);
    float inv = 1.f / sm;
    float invq[4];
#pragma unroll
    for (int r = 0; r < 4; ++r) invq[r] = __shfl(inv, lhi * 4 + r);

    // PV: pack P in-lane (no LDS), accumulate
    f32x4 o[4];
#pragma unroll
    for (int nf = 0; nf < 4; ++nf) o[nf] = (f32x4){0.f, 0.f, 0.f, 0.f};
#pragma unroll
    for (int kc2 = 0; kc2 < 8; ++kc2) {
      if (kc2 >= nk) continue;
      union { bf16x8 v; __hip_bfloat162 h2[4]; } pu;
      pu.h2[0] = __float22bfloat162_rn(make_float2(s[2*kc2][0],   s[2*kc2][1]));
      pu.h2[1] = __float22bfloat162_rn(make_float2(s[2*kc2][2],   s[2*kc2][3]));
      pu.h2[2] = __float22bfloat162_rn(make_float2(s[2*kc2+1][0], s[2*kc2+1][1]));
      pu.h2[3] = __float22bfloat162_rn(make_float2(s[2*kc2+1][2], s[2*kc2+1][3]));
      int kofs = kc2 * 32 + lhi * 8;
      __builtin_amdgcn_s_setprio(1);
#pragma unroll
      for (int nf = 0; nf < 4; ++nf) {
        int hrow = nf * 16 + l15;
        bf16x8 vb = *(const bf16x8*)(Vt + hrow * 256 + (kofs ^ ((hrow & 7) << 3)));
        o[nf] = __builtin_amdgcn_mfma_f32_16x16x32_bf16(pu.v, vb, o[nf], 0, 0, 0);
      }
      __builtin_amdgcn_s_setprio(0);
    }

    // store (divide by row sum here)
#pragma unroll
    for (int nf = 0; nf < 4; ++nf)
#pragma unroll
      for (int r = 0; r < 4; ++r) {
        int q = qrow0 + lhi * 4 + r;
        int h = nf * 16 + l15;
        out[obase + (size_t)q * HH + h] = o[nf][r] * invq[r];
      }
  }
}

extern "C" void kernel_launch(void* const* d_in, const int* in_sizes, int n_in,
                              void* d_out, int out_size, void* d_ws, size_t ws_size,
                              hipStream_t stream) {
  const float* x  = (const float*)d_in[0];
  const float* Wq = (const float*)d_in[1];
  const float* Wk = (const float*)d_in[2];
  const float* Wv = (const float*)d_in[3];
  float* out = (float*)d_out;

  short* wfrag = (short*)d_ws;

  prep_w_kernel<<<36, 256, 0, stream>>>(Wq, Wk, Wv, wfrag);
  fused_kernel<<<512, 512, 0, stream>>>(x, wfrag, out);
}

// Round 10
// 56.994 us; speedup vs baseline: 1.3419x; 1.0563x over previous
//
#include <hip/hip_runtime.h>
#include <hip/hip_bf16.h>

// Problem: B=512, S=256, E=384, H=64.
// d_in: x [B,S,E] f32; Wq,Wk,Wv [E,H] f32.  d_out: [B,S,H] f32.
// ws: [0, 147456) wfrag bf16 (only region used).
//
// FUSED v10 = v7 (57.4us champion) + ONE change: vmcnt-preserving barriers.
// __syncthreads() lowers to "s_waitcnt vmcnt(0) lgkmcnt(0); s_barrier" --
// it force-drains the in-flight x loads once per chunk, capping proj HBM
// duty at ~85% (48KB needs ~4100cy at the per-CU BW share; compute is only
// ~700cy of cover). All cross-wave communication here is via LDS, and the
// in-flight global loads are wave-private register destinations -- so a
// barrier that waits only lgkmcnt(0) is sufficient and lets the HBM stream
// ride through. The compiler still inserts vmcnt waits before each use of
// the loaded registers in writech.

#define NB   512
#define SS   256
#define EE   384
#define HH   64

#define PR16  16            // x rows staged per chunk per group
#define LROW  392           // staging row stride in shorts (384 data + 8 pad)
#define XLSZ  (PR16 * LROW) // 6272 shorts per staging buffer

// lgkm-only barrier: LDS writes retired, global loads ride through.
#define SYNC_LDS() asm volatile("s_waitcnt lgkmcnt(0)\n\ts_barrier" ::: "memory")

typedef short bf16x8 __attribute__((ext_vector_type(8)));
typedef float f32x4  __attribute__((ext_vector_type(4)));

__device__ __forceinline__ short f2bf(float f) {
  union { float f; unsigned u; } x; x.f = f;
  unsigned r = x.u + 0x7fffu + ((x.u >> 16) & 1u);
  return (short)(r >> 16);
}

// ---------------- prep: W -> fragment-ordered bf16 (unchanged) ----------------
// wfrag[((ks*12+nf)*64 + lane)*8 + j] = Wcat[ks*32 + (lane>>4)*8 + j][nf*16 + (lane&15)]
__global__ __launch_bounds__(256) void prep_w_kernel(
    const float* __restrict__ Wq, const float* __restrict__ Wk,
    const float* __restrict__ Wv, short* __restrict__ wfrag) {
  int t = blockIdx.x * 256 + threadIdx.x;
  if (t >= 12 * 12 * 64) return;
  int ks  = t / (12 * 64);
  int rem = t % (12 * 64);
  int nf  = rem / 64;
  int l   = rem % 64;
  int l15 = l & 15, lhi = l >> 4;
  int ncat = nf * 16 + l15;
  const float* W = (ncat < 64) ? Wq : (ncat < 128 ? Wk : Wv);
  int n = ncat & 63;
  short* dst = wfrag + (size_t)t * 8;
#pragma unroll
  for (int j = 0; j < 8; ++j) {
    int kk = ks * 32 + lhi * 8 + j;
    dst[j] = f2bf(W[kk * 64 + n]);
  }
}

// ---------------- fused: one block = one batch, 8 waves, 148 KB LDS ----------------
__global__ __launch_bounds__(512, 2) void fused_kernel(
    const float* __restrict__ x, const short* __restrict__ wfrag,
    float* __restrict__ out) {
  // Ql swizzled: elem (row,h) at Ql[row*64 + (h ^ ((row&7)<<3))]       (v2/v5/v7-verified)
  // Kl swizzled: elem (row,h) at Kl[row*64 + (h ^ (srow<<3))],
  //              srow = ((row&8)>>1)|(row&3)                           (v4..v7-verified)
  // Vt swizzled: elem (h,row) at Vt[h*256 + (row ^ ((h&7)<<3))]        (v2..v7-verified)
  // xst: per group g, dbuf of 16-row tiles, padded stride LROW=392     (v2/v7-verified)
  __shared__ __align__(16) short Ql[SS * HH];    // 32 KB
  __shared__ __align__(16) short Kl[SS * HH];    // 32 KB
  __shared__ __align__(16) short Vt[HH * SS];    // 32 KB
  __shared__ __align__(16) short xst[4 * XLSZ];  // 49 KB -> 148480 B total

  int b    = blockIdx.x;
  int tid  = threadIdx.x;
  int lane = tid & 63, wv = tid >> 6;            // wv in [0,8)
  int l15  = lane & 15, lhi = lane >> 4;
  int sw   = l15 & 7;
  int g    = wv >> 2;                            // row group: rows [g*128, g*128+128)
  int wg   = wv & 3;                             // col-split role: h-tiles f = wg*3+ht
  int tg   = tid & 255;                          // thread index within group
  const float* xg = x + (size_t)b * SS * EE + (size_t)g * 128 * EE;

  // ---- W fragments resident: 3 h-tiles/wave, 36 x bf16x8 = 144 VGPR, pinned ----
  bf16x8 af[12][3];
#pragma unroll
  for (int ks = 0; ks < 12; ++ks)
#pragma unroll
    for (int ht = 0; ht < 3; ++ht)
      af[ks][ht] = *(const bf16x8*)(wfrag + ((size_t)(ks * 12 + wg * 3 + ht) * 64 + lane) * 8);
  // Pin af: allocator cannot rematerialize the wfrag loads in the K-loop
  // (v5/v6/v8 failure mode: VGPR_Count < af size, per-MFMA reloads).
#pragma unroll
  for (int ks = 0; ks < 12; ++ks)
#pragma unroll
    for (int ht = 0; ht < 3; ++ht)
      asm volatile("" : "+v"(af[ks][ht]));

  f32x4 st[6];
  auto loadch = [&](int ch) {  // 16 rows = 24 KB f32 per group, fully contiguous
    const float* p0 = xg + (size_t)ch * PR16 * EE;
#pragma unroll
    for (int i = 0; i < 3; ++i) {
      const f32x4* p = (const f32x4*)(p0 + (size_t)(tg + 256 * i) * 8);
      st[2 * i]     = p[0];
      st[2 * i + 1] = p[1];
    }
  };
  auto writech = [&](short* xl) {  // regs -> bf16 -> padded LDS tile (v2-verified)
#pragma unroll
    for (int i = 0; i < 3; ++i) {
      int c = tg + 256 * i;          // 8-float group: row = c/48, cg = c%48
      int row = c / 48, cg = c % 48;
      union { bf16x8 vv; __hip_bfloat162 h2[4]; } u;
      u.h2[0] = __float22bfloat162_rn(make_float2(st[2*i][0],   st[2*i][1]));
      u.h2[1] = __float22bfloat162_rn(make_float2(st[2*i][2],   st[2*i][3]));
      u.h2[2] = __float22bfloat162_rn(make_float2(st[2*i+1][0], st[2*i+1][1]));
      u.h2[3] = __float22bfloat162_rn(make_float2(st[2*i+1][2], st[2*i+1][3]));
      *(bf16x8*)(xl + row * LROW + cg * 8) = u.vv;
    }
  };

  // ---- projection: 8 chunks of 16 rows/group, dbuf, ONE lgkm-barrier per chunk ----
  // Single-barrier safety (v7-verified): writech(ch+1) targets the opposite
  // buffer of the one being read; reads of that buffer happened in iteration
  // ch-1 and are retired by the barrier at iteration ch's top.
  loadch(0);
  writech(xst + (g * 2) * XLSZ);
  for (int ch = 0; ch < 8; ++ch) {
    if (ch < 7) loadch(ch + 1);      // issue next chunk's loads; they RIDE THROUGH
    SYNC_LDS();                      // LDS visible; vmcnt untouched -> HBM streams on
    const short* xl = xst + (g * 2 + (ch & 1)) * XLSZ;

    f32x4 acc[3];
#pragma unroll
    for (int ht = 0; ht < 3; ++ht) acc[ht] = (f32x4){0.f, 0.f, 0.f, 0.f};
#pragma unroll
    for (int ks = 0; ks < 12; ++ks) {
      bf16x8 bx = *(const bf16x8*)(xl + l15 * LROW + ks * 32 + lhi * 8);
#pragma unroll
      for (int ht = 0; ht < 3; ++ht)
        acc[ht] = __builtin_amdgcn_mfma_f32_16x16x32_bf16(af[ks][ht], bx, acc[ht], 0, 0, 0);
    }

    // epilogue: f = wg*3+ht (wave-uniform), ncat = f*16+lhi*4, row = g*128+ch*16+l15
    int row  = g * 128 + ch * PR16 + l15;
    int srow = ((row & 8) >> 1) | (row & 3);
#pragma unroll
    for (int ht = 0; ht < 3; ++ht) {
      int f = wg * 3 + ht;
      int ncat = f * 16 + lhi * 4;
      if (f < 4) {          // Q -> Ql, row&7 swizzle
        union { short4 s4; __hip_bfloat162 h2[2]; } oq;
        oq.h2[0] = __float22bfloat162_rn(make_float2(acc[ht][0], acc[ht][1]));
        oq.h2[1] = __float22bfloat162_rn(make_float2(acc[ht][2], acc[ht][3]));
        *(short4*)(Ql + row * 64 + (ncat ^ ((row & 7) << 3))) = oq.s4;
      } else if (f < 8) {   // K -> Kl, srow swizzle
        int col = ncat - 64;
        union { short4 s4; __hip_bfloat162 h2[2]; } ok;
        ok.h2[0] = __float22bfloat162_rn(make_float2(acc[ht][0], acc[ht][1]));
        ok.h2[1] = __float22bfloat162_rn(make_float2(acc[ht][2], acc[ht][3]));
        *(short4*)(Kl + row * 64 + (col ^ (srow << 3))) = ok.s4;
      } else {              // V -> Vt transposed, scalar stores
#pragma unroll
        for (int j = 0; j < 4; ++j) {
          int h = ncat - 128 + j;
          Vt[h * 256 + (row ^ ((h & 7) << 3))] = f2bf(acc[ht][j]);
        }
      }
    }
    if (ch < 7) writech(xst + (g * 2 + ((ch + 1) & 1)) * XLSZ);
  }
  SYNC_LDS();                        // Ql/Kl/Vt complete (9th and last barrier)

  // ---- attention: tiles {wv, 15-wv}, in-lane P, zero barriers (v7-verified) ----
  size_t obase = (size_t)b * SS * HH;
#pragma unroll
  for (int u = 0; u < 2; ++u) {
    int rt    = (u == 0) ? wv : (15 - wv);
    int qrow0 = rt * 16;
    int twp   = (rt + 2) & ~1;       // even # of interleaved 16-row k-tiles
    int nk    = twp >> 1;            // 32-k PV chunks
    int qg    = qrow0 + l15;         // this lane's q-row (P lives at q=l15)

    // Q fragments from swizzled Ql
    int qlrow = qrow0 + l15;
    bf16x8 qa0 = *(const bf16x8*)(Ql + qlrow * 64 + ((lhi * 8) ^ ((qlrow & 7) << 3)));
    bf16x8 qa1 = *(const bf16x8*)(Ql + qlrow * 64 + ((32 + lhi * 8) ^ ((qlrow & 7) << 3)));

    // scores: tile t loads K rows kc = (t>>1)*32 + (l15>>2)*8 + (t&1)*4 + (l15&3)
    // (interleaved mapping: srow(kc) == sw, and D-layout == PV A-fragment)
    f32x4 s[16];
#pragma unroll
    for (int t = 0; t < 16; ++t) {
      if (t >= twp) continue;
      int kc = (t >> 1) * 32 + ((l15 >> 2) << 3) + ((t & 1) << 2) + (l15 & 3);
      const short* kp = Kl + kc * 64;
      bf16x8 kb0 = *(const bf16x8*)(kp + ((lhi * 8) ^ (sw << 3)));
      bf16x8 kb1 = *(const bf16x8*)(kp + ((32 + lhi * 8) ^ (sw << 3)));
      __builtin_amdgcn_s_setprio(1);
      f32x4 a = (f32x4){0.f, 0.f, 0.f, 0.f};
      a = __builtin_amdgcn_mfma_f32_16x16x32_bf16(kb0, qa0, a, 0, 0, 0);
      a = __builtin_amdgcn_mfma_f32_16x16x32_bf16(kb1, qa1, a, 0, 0, 0);
      __builtin_amdgcn_s_setprio(0);
#pragma unroll
      for (int r = 0; r < 4; ++r) {
        int kg = (t >> 1) * 32 + lhi * 8 + ((t & 1) << 2) + r;
        s[t][r] = (kg <= qg) ? a[r] * 0.125f : -INFINITY;
      }
    }

    // softmax over lane-local row (q=l15), reduce across lhi groups
    float mx = -3.0e38f;
#pragma unroll
    for (int t = 0; t < 16; ++t) {
      if (t >= twp) continue;
#pragma unroll
      for (int r = 0; r < 4; ++r) mx = fmaxf(mx, s[t][r]);
    }
    mx = fmaxf(mx, __shfl_xor(mx, 16));
    mx = fmaxf(mx, __shfl_xor(mx, 32));
    float sm = 0.f;
#pragma unroll
    for (int t = 0; t < 16; ++t) {
      if (t >= twp) continue;
#pragma unroll
      for (int r = 0; r < 4; ++r) {
        float p = __expf(s[t][r] - mx);    // exp(-inf)=0
        s[t][r] = p;
        sm += p;
      }
    }
    sm += __shfl_xor(sm, 16);
    sm += __shfl_xor(sm, 32);
    float inv = 1.f / sm;
    float invq[4];
#pragma unroll
    for (int r = 0; r < 4; ++r) invq[r] = __shfl(inv, lhi * 4 + r);

    // PV: pack P in-lane (no LDS), accumulate
    f32x4 o[4];
#pragma unroll
    for (int nf = 0; nf < 4; ++nf) o[nf] = (f32x4){0.f, 0.f, 0.f, 0.f};
#pragma unroll
    for (int kc2 = 0; kc2 < 8; ++kc2) {
      if (kc2 >= nk) continue;
      union { bf16x8 v; __hip_bfloat162 h2[4]; } pu;
      pu.h2[0] = __float22bfloat162_rn(make_float2(s[2*kc2][0],   s[2*kc2][1]));
      pu.h2[1] = __float22bfloat162_rn(make_float2(s[2*kc2][2],   s[2*kc2][3]));
      pu.h2[2] = __float22bfloat162_rn(make_float2(s[2*kc2+1][0], s[2*kc2+1][1]));
      pu.h2[3] = __float22bfloat162_rn(make_float2(s[2*kc2+1][2], s[2*kc2+1][3]));
      int kofs = kc2 * 32 + lhi * 8;
      __builtin_amdgcn_s_setprio(1);
#pragma unroll
      for (int nf = 0; nf < 4; ++nf) {
        int hrow = nf * 16 + l15;
        bf16x8 vb = *(const bf16x8*)(Vt + hrow * 256 + (kofs ^ ((hrow & 7) << 3)));
        o[nf] = __builtin_amdgcn_mfma_f32_16x16x32_bf16(pu.v, vb, o[nf], 0, 0, 0);
      }
      __builtin_amdgcn_s_setprio(0);
    }

    // store (divide by row sum here)
#pragma unroll
    for (int nf = 0; nf < 4; ++nf)
#pragma unroll
      for (int r = 0; r < 4; ++r) {
        int q = qrow0 + lhi * 4 + r;
        int h = nf * 16 + l15;
        out[obase + (size_t)q * HH + h] = o[nf][r] * invq[r];
      }
  }
}

extern "C" void kernel_launch(void* const* d_in, const int* in_sizes, int n_in,
                              void* d_out, int out_size, void* d_ws, size_t ws_size,
                              hipStream_t stream) {
  const float* x  = (const float*)d_in[0];
  const float* Wq = (const float*)d_in[1];
  const float* Wk = (const float*)d_in[2];
  const float* Wv = (const float*)d_in[3];
  float* out = (float*)d_out;

  short* wfrag = (short*)d_ws;

  prep_w_kernel<<<36, 256, 0, stream>>>(Wq, Wk, Wv, wfrag);
  fused_kernel<<<512, 512, 0, stream>>>(x, wfrag, out);
}